// Round 14
// baseline (279.909 us; speedup 1.0000x reference)
//
#include <hip/hip_runtime.h>

typedef __attribute__((ext_vector_type(4))) float  fx4;
typedef __attribute__((ext_vector_type(8))) short  s8;
typedef __attribute__((ext_vector_type(8))) unsigned short u8;
typedef __attribute__((ext_vector_type(8))) _Float16 h8;
typedef __attribute__((ext_vector_type(4))) _Float16 hx4;

#define BD   8
#define CD   256
#define ND   16384
#define NH   8
#define DH   32
#define SCALE 0.17677669529663687f   // 1/sqrt(32)

#define GS     32           // split-K factor
#define GKB    (ND / GS)    // 512 fp32 cols per slab
#define GNSTEP (GKB / 64)   // 8 K-steps of 64 cols

__device__ __forceinline__ unsigned short f2h(float f) {
  _Float16 h = (_Float16)f;
  unsigned short u; __builtin_memcpy(&u, &h, 2); return u;
}

// Tiny zero-fill (fallback path only).
__global__ __launch_bounds__(256) void zero_k(float* __restrict__ p, int n) {
  const int i = blockIdx.x * 256 + threadIdx.x;
  if (i < n) p[i] = 0.f;
}

// G = x x^T via fp16 MFMA, BARRIER-FREE direct-gather version.
// Block (s, b): full 256x256 tile, K-slab s (512 cols), 8 waves of 64x128.
// Each lane loads its MFMA fragments straight from global x (16 rows x 128 B
// contiguous per wave-load) and converts fp32->fp16 in registers. No LDS, no
// barriers: waves run free; intra-block row redundancy (A 2x, B 4x) is L2-hit.
// rsum: A-frag cols per (l4) lane are disjoint, cover all 64/step; shfl_xor
// over l4 then wc==0, l4==0 writes rpart. All acc indices compile-time (#20).
__global__ __launch_bounds__(512) void gram_k(const float* __restrict__ x,
                                              _Float16* __restrict__ Gp,
                                              float* __restrict__ Gsum,
                                              float* __restrict__ r,
                                              float* __restrict__ rpart,
                                              int atomic_mode) {
  const int t = threadIdx.x;
  const int s = blockIdx.x, b = blockIdx.y;
  const int wv = t >> 6, lane = t & 63, l15 = lane & 15, l4 = lane >> 4;
  const int wr = wv >> 1, wc = wv & 1;   // 4 row-groups x 2 col-groups (64x128/wave)
  const float* xb = x + (size_t)b * CD * ND + s * GKB;

  fx4 acc[4][8];
#pragma unroll
  for (int i = 0; i < 4; ++i)
#pragma unroll
    for (int j = 0; j < 8; ++j)
      acc[i][j] = (fx4){0.f, 0.f, 0.f, 0.f};

  fx4 racc[4];
#pragma unroll
  for (int i = 0; i < 4; ++i) racc[i] = (fx4){0.f, 0.f, 0.f, 0.f};

#pragma unroll 1
  for (int st = 0; st < GNSTEP; ++st) {
    const int cbase = st * 64 + l4 * 8;
    // ---- A fragments: rows wr*64 + i*16 + l15, cols cbase / cbase+32 ----
    h8 af[4][2];
#pragma unroll
    for (int i = 0; i < 4; ++i) {
      const float* pr = xb + (size_t)(wr * 64 + i * 16 + l15) * ND + cbase;
      fx4 v0 = *(const fx4*)(pr);
      fx4 v1 = *(const fx4*)(pr + 4);
      fx4 v2 = *(const fx4*)(pr + 32);
      fx4 v3 = *(const fx4*)(pr + 36);
      racc[i] += v0 + v1 + v2 + v3;
      hx4 h0 = __builtin_convertvector(v0, hx4);
      hx4 h1 = __builtin_convertvector(v1, hx4);
      hx4 h2 = __builtin_convertvector(v2, hx4);
      hx4 h3 = __builtin_convertvector(v3, hx4);
      af[i][0] = __builtin_shufflevector(h0, h1, 0, 1, 2, 3, 4, 5, 6, 7);
      af[i][1] = __builtin_shufflevector(h2, h3, 0, 1, 2, 3, 4, 5, 6, 7);
    }
    // ---- B fragments + MFMA: rows wc*128 + j*16 + l15 ----
#pragma unroll
    for (int j = 0; j < 8; ++j) {
      const float* pr = xb + (size_t)(wc * 128 + j * 16 + l15) * ND + cbase;
      fx4 v0 = *(const fx4*)(pr);
      fx4 v1 = *(const fx4*)(pr + 4);
      fx4 v2 = *(const fx4*)(pr + 32);
      fx4 v3 = *(const fx4*)(pr + 36);
      hx4 h0 = __builtin_convertvector(v0, hx4);
      hx4 h1 = __builtin_convertvector(v1, hx4);
      hx4 h2 = __builtin_convertvector(v2, hx4);
      hx4 h3 = __builtin_convertvector(v3, hx4);
      h8 b0 = __builtin_shufflevector(h0, h1, 0, 1, 2, 3, 4, 5, 6, 7);
      h8 b1 = __builtin_shufflevector(h2, h3, 0, 1, 2, 3, 4, 5, 6, 7);
#pragma unroll
      for (int i = 0; i < 4; ++i)
        acc[i][j] = __builtin_amdgcn_mfma_f32_16x16x32_f16(af[i][0], b0, acc[i][j], 0, 0, 0);
#pragma unroll
      for (int i = 0; i < 4; ++i)
        acc[i][j] = __builtin_amdgcn_mfma_f32_16x16x32_f16(af[i][1], b1, acc[i][j], 0, 0, 0);
    }
  }

  // ---- row sums: horizontal + cross-l4 reduce ----
  float rs[4];
#pragma unroll
  for (int i = 0; i < 4; ++i) {
    rs[i] = racc[i][0] + racc[i][1] + racc[i][2] + racc[i][3];
    rs[i] += __shfl_xor(rs[i], 16);
    rs[i] += __shfl_xor(rs[i], 32);
  }
  if (wc == 0 && l4 == 0) {
    if (atomic_mode) {
#pragma unroll
      for (int i = 0; i < 4; ++i)
        atomicAdd(&r[b * CD + wr * 64 + i * 16 + l15], rs[i]);
    } else {
#pragma unroll
      for (int i = 0; i < 4; ++i)
        rpart[((size_t)(b * GS + s)) * CD + wr * 64 + i * 16 + l15] = rs[i];
    }
  }

  if (atomic_mode) {
    float* Gb = Gsum + (size_t)b * CD * CD;
#pragma unroll
    for (int i = 0; i < 4; ++i)
#pragma unroll
      for (int j = 0; j < 8; ++j)
#pragma unroll
        for (int q = 0; q < 4; ++q) {
          const int gr = wr * 64 + i * 16 + l4 * 4 + q;
          const int gc = wc * 128 + j * 16 + l15;
          atomicAdd(&Gb[gr * CD + gc], acc[i][j][q]);
        }
  } else {
    _Float16* Gb = Gp + ((size_t)(b * GS + s)) * CD * CD;
#pragma unroll
    for (int i = 0; i < 4; ++i)
#pragma unroll
      for (int j = 0; j < 8; ++j)
#pragma unroll
        for (int q = 0; q < 4; ++q) {
          const int gr = wr * 64 + i * 16 + l4 * 4 + q;
          const int gc = wc * 128 + j * 16 + l15;
          Gb[gr * CD + gc] = (_Float16)acc[i][j][q];
        }
  }
}

// Gsum[b] = sum_s Gpart[b][s] (fp16 -> fp32); also r[b][c] = sum_s rpart.
__global__ __launch_bounds__(256) void reduce_k(const _Float16* __restrict__ Gpart,
                                                const float* __restrict__ rpart,
                                                float* __restrict__ Gsum,
                                                float* __restrict__ r) {
  const int gid = blockIdx.x * 256 + threadIdx.x;   // 131072 fx4 total
  if (gid < BD * CD) {                              // r reduction (2048 lanes)
    const int bb = gid >> 8, c = gid & 255;
    float a = 0.f;
#pragma unroll
    for (int k = 0; k < GS; ++k)
      a += rpart[((size_t)(bb * GS + k)) * CD + c];
    r[gid] = a;
  }
  const int b = gid >> 14;                          // 16384 fx4 per batch
  const int e = gid & 16383;
  const _Float16* p = Gpart + (size_t)b * GS * 65536 + (size_t)e * 4;
  fx4 sv = (fx4){0.f, 0.f, 0.f, 0.f};
#pragma unroll
  for (int k = 0; k < GS; ++k) {
    hx4 hv = *(const hx4*)(p + (size_t)k * 65536);
#pragma unroll
    for (int q = 0; q < 4; ++q) sv[q] += (float)hv[q];
  }
  *(fx4*)(Gsum + (size_t)b * 65536 + (size_t)e * 4) = sv;
}

// Qt[b][h][dd][c] = sum_m Wq[h*32+dd][m] * G[b][m][c]   (fp32)
__global__ __launch_bounds__(256) void qg_k(const float* __restrict__ Wqkv,
                                            const float* __restrict__ G,
                                            float* __restrict__ Qt) {
  const int cq = blockIdx.x, h = blockIdx.y, b = blockIdx.z;
  const int t = threadIdx.x;
  const int c = cq * 64 + (t & 63);
  const int ms = t >> 6;
  const float* Gb = G + (size_t)b * CD * CD;
  const float* wqb = Wqkv + (size_t)(h * DH) * CD;
  float acc[32];
#pragma unroll
  for (int i = 0; i < 32; ++i) acc[i] = 0.f;
  for (int m = ms * 64; m < ms * 64 + 64; ++m) {
    const float gv = Gb[m * CD + c];
    const float* wq = wqb + m;
#pragma unroll
    for (int dd = 0; dd < 32; ++dd)
      acc[dd] += wq[dd * CD] * gv;
  }
  __shared__ float red[4][32][64];
#pragma unroll
  for (int dd = 0; dd < 32; ++dd) red[ms][dd][t & 63] = acc[dd];
  __syncthreads();
  for (int i = t; i < 32 * 64; i += 256) {
    const int dd = i >> 6, cc = i & 63;
    const float v = red[0][dd][cc] + red[1][dd][cc] + red[2][dd][cc] + red[3][dd][cc];
    Qt[(((size_t)b * NH + h) * DH + dd) * CD + cq * 64 + cc] = v;
  }
}

// S, softmax, and M[o][h*32+e] = sum_dd Wout[o][dd*8+h] * attn[dd][e]
__global__ __launch_bounds__(256) void attn_k(const float* __restrict__ Wqkv,
                                              const float* __restrict__ bqkv,
                                              const float* __restrict__ Wout,
                                              const float* __restrict__ Qt,
                                              const float* __restrict__ r,
                                              float* __restrict__ M) {
  const int h = blockIdx.x, b = blockIdx.y;
  const int t = threadIdx.x;
  __shared__ float S[32][33];
  __shared__ float A[32][33];
  __shared__ float wqr[32], wkr[32];
  __shared__ float wred[64][4];
  const float* rb = r + b * CD;
  {
    const int rowid = t & 63;            // (isk<<5)|dd
    const int q = t >> 6;                // quarter of the 256-c dot
    const int isk = rowid >> 5, dd = rowid & 31;
    const float* w = Wqkv + (size_t)(isk * CD + h * DH + dd) * CD + q * 64;
    const float* rq = rb + q * 64;
    float sv = 0.f;
#pragma unroll
    for (int cc = 0; cc < 64; ++cc) sv += w[cc] * rq[cc];
    wred[rowid][q] = sv;
  }
  __syncthreads();
  if (t < 64) {
    const float sv = wred[t][0] + wred[t][1] + wred[t][2] + wred[t][3];
    if (t >> 5) wkr[t & 31] = sv; else wqr[t & 31] = sv;
  }
  __syncthreads();
  {
    const int dd = t >> 3;
    const float* q = Qt + (((size_t)b * NH + h) * DH + dd) * CD;
    const float bq = bqkv[h * DH + dd];
#pragma unroll
    for (int u = 0; u < 4; ++u) {
      const int e = (t & 7) * 4 + u;
      const float bk = bqkv[CD + h * DH + e];
      const float* kw = Wqkv + (size_t)(CD + h * DH + e) * CD;
      float sv = 0.f;
      for (int cc = 0; cc < CD; ++cc) sv += q[cc] * kw[cc];
      sv += bq * wkr[e] + bk * wqr[dd] + (float)ND * bq * bk;
      S[dd][e] = sv * SCALE;
    }
  }
  __syncthreads();
  if (t < 32) {
    float mx = -1e30f;
#pragma unroll
    for (int e = 0; e < 32; ++e) mx = fmaxf(mx, S[t][e]);
    float sum = 0.f;
#pragma unroll
    for (int e = 0; e < 32; ++e) sum += __expf(S[t][e] - mx);
    const float inv = 1.f / sum;
#pragma unroll
    for (int e = 0; e < 32; ++e) A[t][e] = __expf(S[t][e] - mx) * inv;
  }
  __syncthreads();
  {
    float wrow[32];
#pragma unroll
    for (int dd = 0; dd < 32; ++dd) wrow[dd] = Wout[(size_t)t * CD + dd * NH + h];
    for (int e = 0; e < 32; ++e) {
      float sv = 0.f;
#pragma unroll
      for (int dd = 0; dd < 32; ++dd) sv += wrow[dd] * A[dd][e];
      M[((size_t)b * CD + t) * CD + h * DH + e] = sv;
    }
  }
}

// P = M @ Wv stored fp16 in MFMA-fragment order Pf[b][kq][o][8] (kq = c>>3),
// cvec = M @ bv + bout.
__global__ __launch_bounds__(256) void pproj_k(const float* __restrict__ Wqkv,
                                               const float* __restrict__ bqkv,
                                               const float* __restrict__ bout,
                                               const float* __restrict__ M,
                                               unsigned short* __restrict__ Pf,
                                               float* __restrict__ cvec) {
  const int oq = blockIdx.x, b = blockIdx.y;
  const int t = threadIdx.x;                 // t = c
  const float* Mb = M + (size_t)b * CD * CD + oq * 16 * CD;
  const float* Wv = Wqkv + (size_t)2 * CD * CD;
  float acc[16];
#pragma unroll
  for (int i = 0; i < 16; ++i) acc[i] = 0.f;
  for (int m = 0; m < CD; ++m) {
    const float wvv = Wv[(size_t)m * CD + t];
#pragma unroll
    for (int o = 0; o < 16; ++o) acc[o] += Mb[o * CD + m] * wvv;
  }
#pragma unroll
  for (int o = 0; o < 16; ++o) {
    const int oo = oq * 16 + o;
    Pf[(((size_t)b * 32 + (t >> 3)) * 256 + oo) * 8 + (t & 7)] = f2h(acc[o]);
  }
  if (t < 16) {
    const int oo = oq * 16 + t;
    const float* mr = M + (size_t)b * CD * CD + oo * CD;
    float sv = bout[oo];
    for (int m = 0; m < CD; ++m) sv += mr[m] * bqkv[2 * CD + m];
    cvec[b * CD + oo] = sv;
  }
}

// out[b][o][n] = sum_c P[o][c] * fp16(x[b][c][n]) + cvec[b][o]
// Tile: 256 o x 128 n, K=256 fully LDS-resident -> barrier-free K-loop.
__global__ __launch_bounds__(512) void out_k(const float* __restrict__ x,
                                             const unsigned short* __restrict__ Pf,
                                             const float* __restrict__ cvec,
                                             float* __restrict__ out) {
  __shared__ unsigned short xT[128 * 256];   // 64 KB
  const int t = threadIdx.x;
  const int nb = blockIdx.x, b = blockIdx.y;
  const int n0 = nb * 128;
  const int w = t >> 6, l = t & 63, l15 = l & 15, l4 = l >> 4;

  {
    const int nbase = (w & 1) * 64 + l15 * 4;
    const int cb0   = (w >> 1) * 16 + l4 * 4;
#pragma unroll
    for (int it = 0; it < 4; ++it) {
      const int cb = cb0 + it * 64;
      const float* p = x + ((size_t)b * CD + cb) * ND + n0 + nbase;
      fx4 r0 = *(const fx4*)(p);
      fx4 r1 = *(const fx4*)(p + ND);
      fx4 r2 = *(const fx4*)(p + 2 * (size_t)ND);
      fx4 r3 = *(const fx4*)(p + 3 * (size_t)ND);
#pragma unroll
      for (int j = 0; j < 4; ++j) {
        const unsigned long long wlo =
            (unsigned long long)f2h(r0[j]) |
            ((unsigned long long)f2h(r1[j]) << 16) |
            ((unsigned long long)f2h(r2[j]) << 32) |
            ((unsigned long long)f2h(r3[j]) << 48);
        const int n = nbase + j;
        const int slot = ((cb >> 3) ^ (n & 15)) & 31;
        *(unsigned long long*)(&xT[n * 256 + slot * 8 + (cb & 7)]) = wlo;
      }
    }
  }
  __syncthreads();

  const int wr = w >> 1, wc = w & 1;
  fx4 acc[4][4];
#pragma unroll
  for (int i = 0; i < 4; ++i)
#pragma unroll
    for (int j = 0; j < 4; ++j) acc[i][j] = (fx4){0.f, 0.f, 0.f, 0.f};

  const unsigned short* Pb = Pf + (size_t)b * 32 * 256 * 8;
  h8 afc[4], afn[4];
#pragma unroll
  for (int i = 0; i < 4; ++i) {
    const int o = wr * 64 + i * 16 + l15;
    afc[i] = *(const h8*)(Pb + ((size_t)(l4) * 256 + o) * 8);
  }
#pragma unroll
  for (int st = 0; st < 8; ++st) {
    if (st < 7) {
      const int kq = (st + 1) * 4 + l4;
#pragma unroll
      for (int i = 0; i < 4; ++i) {
        const int o = wr * 64 + i * 16 + l15;
        afn[i] = *(const h8*)(Pb + ((size_t)kq * 256 + o) * 8);
      }
    }
#pragma unroll
    for (int j = 0; j < 4; ++j) {
      const int n = wc * 64 + j * 16 + l15;
      const int slot = ((st * 4 + l4) ^ (n & 15)) & 31;
      h8 bf_ = *(const h8*)(&xT[n * 256 + slot * 8]);
#pragma unroll
      for (int i = 0; i < 4; ++i)
        acc[i][j] = __builtin_amdgcn_mfma_f32_16x16x32_f16(afc[i], bf_, acc[i][j], 0, 0, 0);
    }
#pragma unroll
    for (int i = 0; i < 4; ++i) afc[i] = afn[i];
  }

  const float* cp = cvec + b * CD;
  float* ob = out + (size_t)b * CD * ND + n0;
#pragma unroll
  for (int i = 0; i < 4; ++i)
#pragma unroll
    for (int q = 0; q < 4; ++q) {
      const int o = wr * 64 + i * 16 + l4 * 4 + q;
      const float ad = cp[o];
#pragma unroll
      for (int j = 0; j < 4; ++j) {
        const int n = wc * 64 + j * 16 + l15;
        __builtin_nontemporal_store(acc[i][j][q] + ad, &ob[(size_t)o * ND + n]);
      }
    }
}

extern "C" void kernel_launch(void* const* d_in, const int* in_sizes, int n_in,
                              void* d_out, int out_size, void* d_ws, size_t ws_size,
                              hipStream_t stream) {
  const float* x    = (const float*)d_in[0];
  const float* Wqkv = (const float*)d_in[1];
  const float* bqkv = (const float*)d_in[2];
  const float* Wout = (const float*)d_in[3];
  const float* bout = (const float*)d_in[4];
  float* out = (float*)d_out;

  char* ws = (char*)d_ws;
  float*          Gsum = (float*)(ws + 0);                // 2 MB
  float*          r    = (float*)(ws + 2097152);          // 8 KB
  float*          rpart= (float*)(ws + 2105344);          // 256 KB
  float*          Qt   = (float*)(ws + 2367488);          // 2 MB
  float*          Mm   = (float*)(ws + 4464640);          // 2 MB
  unsigned short* Pf   = (unsigned short*)(ws + 6561792); // 1 MB
  float*          cvec = (float*)(ws + 7610368);          // 8 KB
  _Float16*       Gpart= (_Float16*)(ws + 7618560);       // 32 MB (fp16, GS=32)
  const size_t NEED = 7618560ULL + (size_t)BD * GS * CD * CD * 2;  // ~41.2 MB

  const bool partial = (ws_size >= NEED);
  if (partial) {
    gram_k<<<dim3(GS, BD), 512, 0, stream>>>(x, Gpart, Gsum, r, rpart, 0);
    reduce_k<<<dim3(512), 256, 0, stream>>>(Gpart, rpart, Gsum, r);
  } else {
    zero_k<<<dim3(2056), 256, 0, stream>>>(Gsum, 526336);  // Gsum + r
    gram_k<<<dim3(GS, BD), 512, 0, stream>>>(x, Gpart, Gsum, r, rpart, 1);
  }
  qg_k   <<<dim3(4, NH, BD),  256, 0, stream>>>(Wqkv, Gsum, Qt);
  attn_k <<<dim3(NH, BD),     256, 0, stream>>>(Wqkv, bqkv, Wout, Qt, r, Mm);
  pproj_k<<<dim3(16, BD),     256, 0, stream>>>(Wqkv, bqkv, bout, Mm, Pf, cvec);
  out_k  <<<dim3(ND / 128, BD), 512, 0, stream>>>(x, Pf, cvec, out);
}

// Round 15
// 218.267 us; speedup vs baseline: 1.2824x; 1.2824x over previous
//
#include <hip/hip_runtime.h>

typedef __attribute__((ext_vector_type(4))) float  fx4;
typedef __attribute__((ext_vector_type(8))) unsigned short u8;
typedef __attribute__((ext_vector_type(8))) _Float16 h8;
typedef __attribute__((ext_vector_type(4))) _Float16 hx4;

#define BD   8
#define CD   256
#define ND   16384
#define NH   8
#define DH   32
#define SCALE 0.17677669529663687f   // 1/sqrt(32)

#define GS     32           // split-K factor
#define GKB    (ND / GS)    // 512 fp32 cols per slab
#define GNSTEP (GKB / 32)   // 16 K-steps of 32 cols

#define GLOAD(dst, src)                                                        \
  __builtin_amdgcn_global_load_lds(                                            \
      (const __attribute__((address_space(1))) void*)(src),                    \
      (__attribute__((address_space(3))) void*)(dst), 16, 0, 0)

__device__ __forceinline__ unsigned short f2h(float f) {
  _Float16 h = (_Float16)f;
  unsigned short u; __builtin_memcpy(&u, &h, 2); return u;
}

__device__ __forceinline__ h8 cvt2(fx4 v0, fx4 v1) {
  hx4 h0 = __builtin_convertvector(v0, hx4);
  hx4 h1 = __builtin_convertvector(v1, hx4);
  return __builtin_shufflevector(h0, h1, 0, 1, 2, 3, 4, 5, 6, 7);
}

// Workgroup barrier WITHOUT the vmcnt(0) drain __syncthreads emits.
__device__ __forceinline__ void wg_barrier() {
  asm volatile("s_waitcnt lgkmcnt(0)" ::: "memory");
  __builtin_amdgcn_s_barrier();
  __builtin_amdgcn_sched_barrier(0);
}

// Tiny zero-fill (fallback path only).
__global__ __launch_bounds__(256) void zero_k(float* __restrict__ p, int n) {
  const int i = blockIdx.x * 256 + threadIdx.x;
  if (i < n) p[i] = 0.f;
}

// G = x x^T via fp16 MFMA with global_load_lds DMA staging (m97 pattern).
// Block (s, b): full 256x256 tile, K-slab s (512 cols), 8 waves of 64x128.
// LDS: 2 x 32KB fp32 buffers [256 rows][32 cols], col-group XOR swizzle
// cg' = cg ^ (row&7) baked into the per-lane DMA SOURCE address (LDS dest
// stays linear per gload_lds semantics); reads apply the same XOR.
// Counted vmcnt(4): next step's 4 DMA issues stay in flight across the
// barrier (T4); fp32->fp16 conversion happens on the read side.
// All acc indices compile-time (rule #20).
__global__ __launch_bounds__(512) void gram_k(const float* __restrict__ x,
                                              _Float16* __restrict__ Gp,
                                              float* __restrict__ Gsum,
                                              float* __restrict__ r,
                                              float* __restrict__ rpart,
                                              int atomic_mode) {
  __shared__ __align__(16) float sb[2][256 * 32];   // 2 x 32 KB
  const int t = threadIdx.x;
  const int s = blockIdx.x, b = blockIdx.y;
  const int wv = t >> 6, lane = t & 63, l15 = lane & 15, l4 = lane >> 4;
  const int wr = wv >> 1, wc = wv & 1;   // 4 row-groups x 2 col-groups (64x128/wave)
  const float* xb = x + (size_t)b * CD * ND + s * GKB;

  // DMA source mapping: issue k covers LDS rows wv*32 + k*8 + (lane>>3),
  // lane's 16B slot cg' = lane&7 holds source col-group cg = cg' ^ (row&7).
  const int r_off = lane >> 3;          // 0..7
  const int cgp   = lane & 7;

  fx4 acc[4][8];
#pragma unroll
  for (int i = 0; i < 4; ++i)
#pragma unroll
    for (int j = 0; j < 8; ++j)
      acc[i][j] = (fx4){0.f, 0.f, 0.f, 0.f};

  fx4 racc[4];
#pragma unroll
  for (int i = 0; i < 4; ++i) racc[i] = (fx4){0.f, 0.f, 0.f, 0.f};

  // ---- prologue: DMA step 0 into buf0 ----
#pragma unroll
  for (int k = 0; k < 4; ++k) {
    const int row = wv * 32 + k * 8 + r_off;
    const int cg  = cgp ^ (row & 7);
    GLOAD(&sb[0][wv * 1024 + k * 256], xb + (size_t)row * ND + cg * 4);
  }

#pragma unroll 1
  for (int st = 0; st < GNSTEP; ++st) {
    const float* bp = &sb[st & 1][0];
    if (st + 1 < GNSTEP) {
      // issue next step's DMA, then wait only for THIS step's 4 (counted)
#pragma unroll
      for (int k = 0; k < 4; ++k) {
        const int row = wv * 32 + k * 8 + r_off;
        const int cg  = cgp ^ (row & 7);
        GLOAD(&sb[(st + 1) & 1][wv * 1024 + k * 256],
              xb + (size_t)row * ND + (st + 1) * 32 + cg * 4);
      }
      asm volatile("s_waitcnt vmcnt(4)" ::: "memory");
    } else {
      asm volatile("s_waitcnt vmcnt(0)" ::: "memory");
    }
    __builtin_amdgcn_sched_barrier(0);
    __builtin_amdgcn_s_barrier();
    __builtin_amdgcn_sched_barrier(0);

    // ---- A fragments (rows wr*64 + i*16 + l15, cols l4*8..+7) ----
    h8 af[4];
#pragma unroll
    for (int i = 0; i < 4; ++i) {
      const int R = wr * 64 + i * 16 + l15;
      const int rs7 = R & 7;
      const float* rp = bp + R * 32;
      fx4 v0 = *(const fx4*)(rp + (((l4 * 2)     ^ rs7) * 4));
      fx4 v1 = *(const fx4*)(rp + (((l4 * 2 + 1) ^ rs7) * 4));
      racc[i] += v0 + v1;
      af[i] = cvt2(v0, v1);
    }
    // ---- B fragments + MFMA (rows wc*128 + j*16 + l15) ----
    __builtin_amdgcn_s_setprio(1);
#pragma unroll
    for (int j = 0; j < 8; ++j) {
      const int Rc = wc * 128 + j * 16 + l15;
      const int rs7 = Rc & 7;
      const float* rp = bp + Rc * 32;
      fx4 v0 = *(const fx4*)(rp + (((l4 * 2)     ^ rs7) * 4));
      fx4 v1 = *(const fx4*)(rp + (((l4 * 2 + 1) ^ rs7) * 4));
      h8 bf = cvt2(v0, v1);
#pragma unroll
      for (int i = 0; i < 4; ++i)
        acc[i][j] = __builtin_amdgcn_mfma_f32_16x16x32_f16(af[i], bf, acc[i][j], 0, 0, 0);
    }
    __builtin_amdgcn_s_setprio(0);
    wg_barrier();    // all waves done reading before next DMA lands
  }

  // ---- row sums: horizontal + cross-l4 reduce (cols disjoint per l4) ----
  float rs[4];
#pragma unroll
  for (int i = 0; i < 4; ++i) {
    rs[i] = racc[i][0] + racc[i][1] + racc[i][2] + racc[i][3];
    rs[i] += __shfl_xor(rs[i], 16);
    rs[i] += __shfl_xor(rs[i], 32);
  }
  if (wc == 0 && l4 == 0) {
    if (atomic_mode) {
#pragma unroll
      for (int i = 0; i < 4; ++i)
        atomicAdd(&r[b * CD + wr * 64 + i * 16 + l15], rs[i]);
    } else {
#pragma unroll
      for (int i = 0; i < 4; ++i)
        rpart[((size_t)(b * GS + s)) * CD + wr * 64 + i * 16 + l15] = rs[i];
    }
  }

  if (atomic_mode) {
    float* Gb = Gsum + (size_t)b * CD * CD;
#pragma unroll
    for (int i = 0; i < 4; ++i)
#pragma unroll
      for (int j = 0; j < 8; ++j)
#pragma unroll
        for (int q = 0; q < 4; ++q) {
          const int gr = wr * 64 + i * 16 + l4 * 4 + q;
          const int gc = wc * 128 + j * 16 + l15;
          atomicAdd(&Gb[gr * CD + gc], acc[i][j][q]);
        }
  } else {
    _Float16* Gb = Gp + ((size_t)(b * GS + s)) * CD * CD;
#pragma unroll
    for (int i = 0; i < 4; ++i)
#pragma unroll
      for (int j = 0; j < 8; ++j)
#pragma unroll
        for (int q = 0; q < 4; ++q) {
          const int gr = wr * 64 + i * 16 + l4 * 4 + q;
          const int gc = wc * 128 + j * 16 + l15;
          Gb[gr * CD + gc] = (_Float16)acc[i][j][q];
        }
  }
}

// Gsum[b] = sum_s Gpart[b][s] (fp16 -> fp32); also r[b][c] = sum_s rpart.
__global__ __launch_bounds__(256) void reduce_k(const _Float16* __restrict__ Gpart,
                                                const float* __restrict__ rpart,
                                                float* __restrict__ Gsum,
                                                float* __restrict__ r) {
  const int gid = blockIdx.x * 256 + threadIdx.x;   // 131072 fx4 total
  if (gid < BD * CD) {                              // r reduction (2048 lanes)
    const int bb = gid >> 8, c = gid & 255;
    float a = 0.f;
#pragma unroll
    for (int k = 0; k < GS; ++k)
      a += rpart[((size_t)(bb * GS + k)) * CD + c];
    r[gid] = a;
  }
  const int b = gid >> 14;                          // 16384 fx4 per batch
  const int e = gid & 16383;
  const _Float16* p = Gpart + (size_t)b * GS * 65536 + (size_t)e * 4;
  fx4 sv = (fx4){0.f, 0.f, 0.f, 0.f};
#pragma unroll
  for (int k = 0; k < GS; ++k) {
    hx4 hv = *(const hx4*)(p + (size_t)k * 65536);
#pragma unroll
    for (int q = 0; q < 4; ++q) sv[q] += (float)hv[q];
  }
  *(fx4*)(Gsum + (size_t)b * 65536 + (size_t)e * 4) = sv;
}

// Qt[b][h][dd][c] = sum_m Wq[h*32+dd][m] * G[b][m][c]   (fp32)
__global__ __launch_bounds__(256) void qg_k(const float* __restrict__ Wqkv,
                                            const float* __restrict__ G,
                                            float* __restrict__ Qt) {
  const int cq = blockIdx.x, h = blockIdx.y, b = blockIdx.z;
  const int t = threadIdx.x;
  const int c = cq * 64 + (t & 63);
  const int ms = t >> 6;
  const float* Gb = G + (size_t)b * CD * CD;
  const float* wqb = Wqkv + (size_t)(h * DH) * CD;
  float acc[32];
#pragma unroll
  for (int i = 0; i < 32; ++i) acc[i] = 0.f;
  for (int m = ms * 64; m < ms * 64 + 64; ++m) {
    const float gv = Gb[m * CD + c];
    const float* wq = wqb + m;
#pragma unroll
    for (int dd = 0; dd < 32; ++dd)
      acc[dd] += wq[dd * CD] * gv;
  }
  __shared__ float red[4][32][64];
#pragma unroll
  for (int dd = 0; dd < 32; ++dd) red[ms][dd][t & 63] = acc[dd];
  __syncthreads();
  for (int i = t; i < 32 * 64; i += 256) {
    const int dd = i >> 6, cc = i & 63;
    const float v = red[0][dd][cc] + red[1][dd][cc] + red[2][dd][cc] + red[3][dd][cc];
    Qt[(((size_t)b * NH + h) * DH + dd) * CD + cq * 64 + cc] = v;
  }
}

// S, softmax, and M[o][h*32+e] = sum_dd Wout[o][dd*8+h] * attn[dd][e]
__global__ __launch_bounds__(256) void attn_k(const float* __restrict__ Wqkv,
                                              const float* __restrict__ bqkv,
                                              const float* __restrict__ Wout,
                                              const float* __restrict__ Qt,
                                              const float* __restrict__ r,
                                              float* __restrict__ M) {
  const int h = blockIdx.x, b = blockIdx.y;
  const int t = threadIdx.x;
  __shared__ float S[32][33];
  __shared__ float A[32][33];
  __shared__ float wqr[32], wkr[32];
  __shared__ float wred[64][4];
  const float* rb = r + b * CD;
  {
    const int rowid = t & 63;            // (isk<<5)|dd
    const int q = t >> 6;                // quarter of the 256-c dot
    const int isk = rowid >> 5, dd = rowid & 31;
    const float* w = Wqkv + (size_t)(isk * CD + h * DH + dd) * CD + q * 64;
    const float* rq = rb + q * 64;
    float sv = 0.f;
#pragma unroll
    for (int cc = 0; cc < 64; ++cc) sv += w[cc] * rq[cc];
    wred[rowid][q] = sv;
  }
  __syncthreads();
  if (t < 64) {
    const float sv = wred[t][0] + wred[t][1] + wred[t][2] + wred[t][3];
    if (t >> 5) wkr[t & 31] = sv; else wqr[t & 31] = sv;
  }
  __syncthreads();
  {
    const int dd = t >> 3;
    const float* q = Qt + (((size_t)b * NH + h) * DH + dd) * CD;
    const float bq = bqkv[h * DH + dd];
#pragma unroll
    for (int u = 0; u < 4; ++u) {
      const int e = (t & 7) * 4 + u;
      const float bk = bqkv[CD + h * DH + e];
      const float* kw = Wqkv + (size_t)(CD + h * DH + e) * CD;
      float sv = 0.f;
      for (int cc = 0; cc < CD; ++cc) sv += q[cc] * kw[cc];
      sv += bq * wkr[e] + bk * wqr[dd] + (float)ND * bq * bk;
      S[dd][e] = sv * SCALE;
    }
  }
  __syncthreads();
  if (t < 32) {
    float mx = -1e30f;
#pragma unroll
    for (int e = 0; e < 32; ++e) mx = fmaxf(mx, S[t][e]);
    float sum = 0.f;
#pragma unroll
    for (int e = 0; e < 32; ++e) sum += __expf(S[t][e] - mx);
    const float inv = 1.f / sum;
#pragma unroll
    for (int e = 0; e < 32; ++e) A[t][e] = __expf(S[t][e] - mx) * inv;
  }
  __syncthreads();
  {
    float wrow[32];
#pragma unroll
    for (int dd = 0; dd < 32; ++dd) wrow[dd] = Wout[(size_t)t * CD + dd * NH + h];
    for (int e = 0; e < 32; ++e) {
      float sv = 0.f;
#pragma unroll
      for (int dd = 0; dd < 32; ++dd) sv += wrow[dd] * A[dd][e];
      M[((size_t)b * CD + t) * CD + h * DH + e] = sv;
    }
  }
}

// P = M @ Wv stored fp16 in MFMA-fragment order Pf[b][kq][o][8] (kq = c>>3),
// cvec = M @ bv + bout.
__global__ __launch_bounds__(256) void pproj_k(const float* __restrict__ Wqkv,
                                               const float* __restrict__ bqkv,
                                               const float* __restrict__ bout,
                                               const float* __restrict__ M,
                                               unsigned short* __restrict__ Pf,
                                               float* __restrict__ cvec) {
  const int oq = blockIdx.x, b = blockIdx.y;
  const int t = threadIdx.x;                 // t = c
  const float* Mb = M + (size_t)b * CD * CD + oq * 16 * CD;
  const float* Wv = Wqkv + (size_t)2 * CD * CD;
  float acc[16];
#pragma unroll
  for (int i = 0; i < 16; ++i) acc[i] = 0.f;
  for (int m = 0; m < CD; ++m) {
    const float wvv = Wv[(size_t)m * CD + t];
#pragma unroll
    for (int o = 0; o < 16; ++o) acc[o] += Mb[o * CD + m] * wvv;
  }
#pragma unroll
  for (int o = 0; o < 16; ++o) {
    const int oo = oq * 16 + o;
    Pf[(((size_t)b * 32 + (t >> 3)) * 256 + oo) * 8 + (t & 7)] = f2h(acc[o]);
  }
  if (t < 16) {
    const int oo = oq * 16 + t;
    const float* mr = M + (size_t)b * CD * CD + oo * CD;
    float sv = bout[oo];
    for (int m = 0; m < CD; ++m) sv += mr[m] * bqkv[2 * CD + m];
    cvec[b * CD + oo] = sv;
  }
}

// out[b][o][n] = sum_c P[o][c] * fp16(x[b][c][n]) + cvec[b][o]
// Tile: 256 o x 128 n, K=256 fully LDS-resident -> barrier-free K-loop.
__global__ __launch_bounds__(512) void out_k(const float* __restrict__ x,
                                             const unsigned short* __restrict__ Pf,
                                             const float* __restrict__ cvec,
                                             float* __restrict__ out) {
  __shared__ unsigned short xT[128 * 256];   // 64 KB
  const int t = threadIdx.x;
  const int nb = blockIdx.x, b = blockIdx.y;
  const int n0 = nb * 128;
  const int w = t >> 6, l = t & 63, l15 = l & 15, l4 = l >> 4;

  {
    const int nbase = (w & 1) * 64 + l15 * 4;
    const int cb0   = (w >> 1) * 16 + l4 * 4;
#pragma unroll
    for (int it = 0; it < 4; ++it) {
      const int cb = cb0 + it * 64;
      const float* p = x + ((size_t)b * CD + cb) * ND + n0 + nbase;
      fx4 r0 = *(const fx4*)(p);
      fx4 r1 = *(const fx4*)(p + ND);
      fx4 r2 = *(const fx4*)(p + 2 * (size_t)ND);
      fx4 r3 = *(const fx4*)(p + 3 * (size_t)ND);
#pragma unroll
      for (int j = 0; j < 4; ++j) {
        const unsigned long long wlo =
            (unsigned long long)f2h(r0[j]) |
            ((unsigned long long)f2h(r1[j]) << 16) |
            ((unsigned long long)f2h(r2[j]) << 32) |
            ((unsigned long long)f2h(r3[j]) << 48);
        const int n = nbase + j;
        const int slot = ((cb >> 3) ^ (n & 15)) & 31;
        *(unsigned long long*)(&xT[n * 256 + slot * 8 + (cb & 7)]) = wlo;
      }
    }
  }
  __syncthreads();

  const int wr = w >> 1, wc = w & 1;
  fx4 acc[4][4];
#pragma unroll
  for (int i = 0; i < 4; ++i)
#pragma unroll
    for (int j = 0; j < 4; ++j) acc[i][j] = (fx4){0.f, 0.f, 0.f, 0.f};

  const unsigned short* Pb = Pf + (size_t)b * 32 * 256 * 8;
  h8 afc[4], afn[4];
#pragma unroll
  for (int i = 0; i < 4; ++i) {
    const int o = wr * 64 + i * 16 + l15;
    afc[i] = *(const h8*)(Pb + ((size_t)(l4) * 256 + o) * 8);
  }
#pragma unroll
  for (int st = 0; st < 8; ++st) {
    if (st < 7) {
      const int kq = (st + 1) * 4 + l4;
#pragma unroll
      for (int i = 0; i < 4; ++i) {
        const int o = wr * 64 + i * 16 + l15;
        afn[i] = *(const h8*)(Pb + ((size_t)kq * 256 + o) * 8);
      }
    }
#pragma unroll
    for (int j = 0; j < 4; ++j) {
      const int n = wc * 64 + j * 16 + l15;
      const int slot = ((st * 4 + l4) ^ (n & 15)) & 31;
      h8 bf_ = *(const h8*)(&xT[n * 256 + slot * 8]);
#pragma unroll
      for (int i = 0; i < 4; ++i)
        acc[i][j] = __builtin_amdgcn_mfma_f32_16x16x32_f16(afc[i], bf_, acc[i][j], 0, 0, 0);
    }
#pragma unroll
    for (int i = 0; i < 4; ++i) afc[i] = afn[i];
  }

  const float* cp = cvec + b * CD;
  float* ob = out + (size_t)b * CD * ND + n0;
#pragma unroll
  for (int i = 0; i < 4; ++i)
#pragma unroll
    for (int q = 0; q < 4; ++q) {
      const int o = wr * 64 + i * 16 + l4 * 4 + q;
      const float ad = cp[o];
#pragma unroll
      for (int j = 0; j < 4; ++j) {
        const int n = wc * 64 + j * 16 + l15;
        __builtin_nontemporal_store(acc[i][j][q] + ad, &ob[(size_t)o * ND + n]);
      }
    }
}

extern "C" void kernel_launch(void* const* d_in, const int* in_sizes, int n_in,
                              void* d_out, int out_size, void* d_ws, size_t ws_size,
                              hipStream_t stream) {
  const float* x    = (const float*)d_in[0];
  const float* Wqkv = (const float*)d_in[1];
  const float* bqkv = (const float*)d_in[2];
  const float* Wout = (const float*)d_in[3];
  const float* bout = (const float*)d_in[4];
  float* out = (float*)d_out;

  char* ws = (char*)d_ws;
  float*          Gsum = (float*)(ws + 0);                // 2 MB
  float*          r    = (float*)(ws + 2097152);          // 8 KB
  float*          rpart= (float*)(ws + 2105344);          // 256 KB
  float*          Qt   = (float*)(ws + 2367488);          // 2 MB
  float*          Mm   = (float*)(ws + 4464640);          // 2 MB
  unsigned short* Pf   = (unsigned short*)(ws + 6561792); // 1 MB
  float*          cvec = (float*)(ws + 7610368);          // 8 KB
  _Float16*       Gpart= (_Float16*)(ws + 7618560);       // 32 MB (fp16, GS=32)
  const size_t NEED = 7618560ULL + (size_t)BD * GS * CD * CD * 2;  // ~41.2 MB

  const bool partial = (ws_size >= NEED);
  if (partial) {
    gram_k<<<dim3(GS, BD), 512, 0, stream>>>(x, Gpart, Gsum, r, rpart, 0);
    reduce_k<<<dim3(512), 256, 0, stream>>>(Gpart, rpart, Gsum, r);
  } else {
    zero_k<<<dim3(2056), 256, 0, stream>>>(Gsum, 526336);  // Gsum + r
    gram_k<<<dim3(GS, BD), 512, 0, stream>>>(x, Gpart, Gsum, r, rpart, 1);
  }
  qg_k   <<<dim3(4, NH, BD),  256, 0, stream>>>(Wqkv, Gsum, Qt);
  attn_k <<<dim3(NH, BD),     256, 0, stream>>>(Wqkv, bqkv, Wout, Qt, r, Mm);
  pproj_k<<<dim3(16, BD),     256, 0, stream>>>(Wqkv, bqkv, bout, Mm, Pf, cvec);
  out_k  <<<dim3(ND / 128, BD), 512, 0, stream>>>(x, Pf, cvec, out);
}

// Round 16
// 217.481 us; speedup vs baseline: 1.2871x; 1.0036x over previous
//
#include <hip/hip_runtime.h>

typedef __attribute__((ext_vector_type(4))) float  fx4;
typedef __attribute__((ext_vector_type(8))) unsigned short u8;
typedef __attribute__((ext_vector_type(8))) _Float16 h8;
typedef __attribute__((ext_vector_type(4))) _Float16 hx4;

#define BD   8
#define CD   256
#define ND   16384
#define NH   8
#define DH   32
#define SCALE 0.17677669529663687f   // 1/sqrt(32)

#define GS     32           // split-K factor
#define GKB    (ND / GS)    // 512 fp32 cols per slab
#define GNSTEP (GKB / 32)   // 16 K-steps of 32 cols

#define GLOAD(dst, src)                                                        \
  __builtin_amdgcn_global_load_lds(                                            \
      (const __attribute__((address_space(1))) void*)(src),                    \
      (__attribute__((address_space(3))) void*)(dst), 16, 0, 0)

__device__ __forceinline__ unsigned short f2h(float f) {
  _Float16 h = (_Float16)f;
  unsigned short u; __builtin_memcpy(&u, &h, 2); return u;
}

__device__ __forceinline__ h8 cvt2(fx4 v0, fx4 v1) {
  hx4 h0 = __builtin_convertvector(v0, hx4);
  hx4 h1 = __builtin_convertvector(v1, hx4);
  return __builtin_shufflevector(h0, h1, 0, 1, 2, 3, 4, 5, 6, 7);
}

// Tiny zero-fill (fallback path only).
__global__ __launch_bounds__(256) void zero_k(float* __restrict__ p, int n) {
  const int i = blockIdx.x * 256 + threadIdx.x;
  if (i < n) p[i] = 0.f;
}

// G = x x^T via fp16 MFMA with global_load_lds DMA staging.
// Block (s, b): full 256x256 tile, K-slab s (512 cols), 8 waves of 64x128.
// 4-buffer LDS rotation (128 KB), ONE barrier per K-step, DMA depth 2:
//   per step: issue DMA(st+2 -> buf[(st+2)&3])   [that buf's readers were
//             step st-2; they drained lgkm before barrier st-1 which all
//             waves passed -> safe]
//             vmcnt(8)  [own st-batch landed; 12 outstanding -> 8]
//             lgkmcnt(0) + s_barrier  [all waves' st-batches landed]
//             compute st.
// Col-group XOR swizzle cg' = cg ^ (row&7) baked into the DMA SOURCE addr
// (LDS dest linear per gload_lds); reads apply the same XOR (rule #21).
// All acc indices compile-time (rule #20).
__global__ __launch_bounds__(512) void gram_k(const float* __restrict__ x,
                                              _Float16* __restrict__ Gp,
                                              float* __restrict__ Gsum,
                                              float* __restrict__ r,
                                              float* __restrict__ rpart,
                                              int atomic_mode) {
  __shared__ __align__(16) float sb[4][256 * 32];   // 4 x 32 KB
  const int t = threadIdx.x;
  const int s = blockIdx.x, b = blockIdx.y;
  const int wv = t >> 6, lane = t & 63, l15 = lane & 15, l4 = lane >> 4;
  const int wr = wv >> 1, wc = wv & 1;   // 4 row-groups x 2 col-groups (64x128/wave)
  const float* xb = x + (size_t)b * CD * ND + s * GKB;

  // DMA mapping: issue k covers LDS rows wv*32 + k*8 + (lane>>3);
  // lane's 16B slot cg' = lane&7 holds source col-group cg = cg' ^ (row&7).
  const int r_off = lane >> 3;          // 0..7
  const int cgp   = lane & 7;

  fx4 acc[4][8];
#pragma unroll
  for (int i = 0; i < 4; ++i)
#pragma unroll
    for (int j = 0; j < 8; ++j)
      acc[i][j] = (fx4){0.f, 0.f, 0.f, 0.f};

  fx4 racc[4];
#pragma unroll
  for (int i = 0; i < 4; ++i) racc[i] = (fx4){0.f, 0.f, 0.f, 0.f};

  // ---- prologue: DMA steps 0,1 into buf0,buf1 ----
#pragma unroll
  for (int k = 0; k < 4; ++k) {
    const int row = wv * 32 + k * 8 + r_off;
    const int cg  = cgp ^ (row & 7);
    GLOAD(&sb[0][wv * 1024 + k * 256], xb + (size_t)row * ND + cg * 4);
  }
#pragma unroll
  for (int k = 0; k < 4; ++k) {
    const int row = wv * 32 + k * 8 + r_off;
    const int cg  = cgp ^ (row & 7);
    GLOAD(&sb[1][wv * 1024 + k * 256], xb + (size_t)row * ND + 32 + cg * 4);
  }

#pragma unroll 1
  for (int st = 0; st < GNSTEP; ++st) {
    const float* bp = &sb[st & 3][0];
    if (st + 2 < GNSTEP) {
#pragma unroll
      for (int k = 0; k < 4; ++k) {
        const int row = wv * 32 + k * 8 + r_off;
        const int cg  = cgp ^ (row & 7);
        GLOAD(&sb[(st + 2) & 3][wv * 1024 + k * 256],
              xb + (size_t)row * ND + (st + 2) * 32 + cg * 4);
      }
      asm volatile("s_waitcnt vmcnt(8)" ::: "memory");
    } else if (st + 1 < GNSTEP) {
      asm volatile("s_waitcnt vmcnt(4)" ::: "memory");
    } else {
      asm volatile("s_waitcnt vmcnt(0)" ::: "memory");
    }
    asm volatile("s_waitcnt lgkmcnt(0)" ::: "memory");
    __builtin_amdgcn_sched_barrier(0);
    __builtin_amdgcn_s_barrier();
    __builtin_amdgcn_sched_barrier(0);

    // ---- A fragments (rows wr*64 + i*16 + l15, cols l4*8..+7) ----
    h8 af[4];
#pragma unroll
    for (int i = 0; i < 4; ++i) {
      const int R = wr * 64 + i * 16 + l15;
      const int rs7 = R & 7;
      const float* rp = bp + R * 32;
      fx4 v0 = *(const fx4*)(rp + (((l4 * 2)     ^ rs7) * 4));
      fx4 v1 = *(const fx4*)(rp + (((l4 * 2 + 1) ^ rs7) * 4));
      racc[i] += v0 + v1;
      af[i] = cvt2(v0, v1);
    }
    // ---- B fragments + MFMA (rows wc*128 + j*16 + l15) ----
    __builtin_amdgcn_s_setprio(1);
#pragma unroll
    for (int j = 0; j < 8; ++j) {
      const int Rc = wc * 128 + j * 16 + l15;
      const int rs7 = Rc & 7;
      const float* rp = bp + Rc * 32;
      fx4 v0 = *(const fx4*)(rp + (((l4 * 2)     ^ rs7) * 4));
      fx4 v1 = *(const fx4*)(rp + (((l4 * 2 + 1) ^ rs7) * 4));
      h8 bf = cvt2(v0, v1);
#pragma unroll
      for (int i = 0; i < 4; ++i)
        acc[i][j] = __builtin_amdgcn_mfma_f32_16x16x32_f16(af[i], bf, acc[i][j], 0, 0, 0);
    }
    __builtin_amdgcn_s_setprio(0);
  }

  // ---- row sums: horizontal + cross-l4 reduce (cols disjoint per l4) ----
  float rs[4];
#pragma unroll
  for (int i = 0; i < 4; ++i) {
    rs[i] = racc[i][0] + racc[i][1] + racc[i][2] + racc[i][3];
    rs[i] += __shfl_xor(rs[i], 16);
    rs[i] += __shfl_xor(rs[i], 32);
  }
  if (wc == 0 && l4 == 0) {
    if (atomic_mode) {
#pragma unroll
      for (int i = 0; i < 4; ++i)
        atomicAdd(&r[b * CD + wr * 64 + i * 16 + l15], rs[i]);
    } else {
#pragma unroll
      for (int i = 0; i < 4; ++i)
        rpart[((size_t)(b * GS + s)) * CD + wr * 64 + i * 16 + l15] = rs[i];
    }
  }

  if (atomic_mode) {
    float* Gb = Gsum + (size_t)b * CD * CD;
#pragma unroll
    for (int i = 0; i < 4; ++i)
#pragma unroll
      for (int j = 0; j < 8; ++j)
#pragma unroll
        for (int q = 0; q < 4; ++q) {
          const int gr = wr * 64 + i * 16 + l4 * 4 + q;
          const int gc = wc * 128 + j * 16 + l15;
          atomicAdd(&Gb[gr * CD + gc], acc[i][j][q]);
        }
  } else {
    _Float16* Gb = Gp + ((size_t)(b * GS + s)) * CD * CD;
#pragma unroll
    for (int i = 0; i < 4; ++i)
#pragma unroll
      for (int j = 0; j < 8; ++j)
#pragma unroll
        for (int q = 0; q < 4; ++q) {
          const int gr = wr * 64 + i * 16 + l4 * 4 + q;
          const int gc = wc * 128 + j * 16 + l15;
          Gb[gr * CD + gc] = (_Float16)acc[i][j][q];
        }
  }
}

// Gsum[b] = sum_s Gpart[b][s] (fp16 -> fp32); also r[b][c] = sum_s rpart.
__global__ __launch_bounds__(256) void reduce_k(const _Float16* __restrict__ Gpart,
                                                const float* __restrict__ rpart,
                                                float* __restrict__ Gsum,
                                                float* __restrict__ r) {
  const int gid = blockIdx.x * 256 + threadIdx.x;   // 131072 fx4 total
  if (gid < BD * CD) {                              // r reduction (2048 lanes)
    const int bb = gid >> 8, c = gid & 255;
    float a = 0.f;
#pragma unroll
    for (int k = 0; k < GS; ++k)
      a += rpart[((size_t)(bb * GS + k)) * CD + c];
    r[gid] = a;
  }
  const int b = gid >> 14;                          // 16384 fx4 per batch
  const int e = gid & 16383;
  const _Float16* p = Gpart + (size_t)b * GS * 65536 + (size_t)e * 4;
  fx4 sv = (fx4){0.f, 0.f, 0.f, 0.f};
#pragma unroll
  for (int k = 0; k < GS; ++k) {
    hx4 hv = *(const hx4*)(p + (size_t)k * 65536);
#pragma unroll
    for (int q = 0; q < 4; ++q) sv[q] += (float)hv[q];
  }
  *(fx4*)(Gsum + (size_t)b * 65536 + (size_t)e * 4) = sv;
}

// Qt[b][h][dd][c] = sum_m Wq[h*32+dd][m] * G[b][m][c]   (fp32)
__global__ __launch_bounds__(256) void qg_k(const float* __restrict__ Wqkv,
                                            const float* __restrict__ G,
                                            float* __restrict__ Qt) {
  const int cq = blockIdx.x, h = blockIdx.y, b = blockIdx.z;
  const int t = threadIdx.x;
  const int c = cq * 64 + (t & 63);
  const int ms = t >> 6;
  const float* Gb = G + (size_t)b * CD * CD;
  const float* wqb = Wqkv + (size_t)(h * DH) * CD;
  float acc[32];
#pragma unroll
  for (int i = 0; i < 32; ++i) acc[i] = 0.f;
  for (int m = ms * 64; m < ms * 64 + 64; ++m) {
    const float gv = Gb[m * CD + c];
    const float* wq = wqb + m;
#pragma unroll
    for (int dd = 0; dd < 32; ++dd)
      acc[dd] += wq[dd * CD] * gv;
  }
  __shared__ float red[4][32][64];
#pragma unroll
  for (int dd = 0; dd < 32; ++dd) red[ms][dd][t & 63] = acc[dd];
  __syncthreads();
  for (int i = t; i < 32 * 64; i += 256) {
    const int dd = i >> 6, cc = i & 63;
    const float v = red[0][dd][cc] + red[1][dd][cc] + red[2][dd][cc] + red[3][dd][cc];
    Qt[(((size_t)b * NH + h) * DH + dd) * CD + cq * 64 + cc] = v;
  }
}

// S, softmax, and M[o][h*32+e] = sum_dd Wout[o][dd*8+h] * attn[dd][e]
__global__ __launch_bounds__(256) void attn_k(const float* __restrict__ Wqkv,
                                              const float* __restrict__ bqkv,
                                              const float* __restrict__ Wout,
                                              const float* __restrict__ Qt,
                                              const float* __restrict__ r,
                                              float* __restrict__ M) {
  const int h = blockIdx.x, b = blockIdx.y;
  const int t = threadIdx.x;
  __shared__ float S[32][33];
  __shared__ float A[32][33];
  __shared__ float wqr[32], wkr[32];
  __shared__ float wred[64][4];
  const float* rb = r + b * CD;
  {
    const int rowid = t & 63;            // (isk<<5)|dd
    const int q = t >> 6;                // quarter of the 256-c dot
    const int isk = rowid >> 5, dd = rowid & 31;
    const float* w = Wqkv + (size_t)(isk * CD + h * DH + dd) * CD + q * 64;
    const float* rq = rb + q * 64;
    float sv = 0.f;
#pragma unroll
    for (int cc = 0; cc < 64; ++cc) sv += w[cc] * rq[cc];
    wred[rowid][q] = sv;
  }
  __syncthreads();
  if (t < 64) {
    const float sv = wred[t][0] + wred[t][1] + wred[t][2] + wred[t][3];
    if (t >> 5) wkr[t & 31] = sv; else wqr[t & 31] = sv;
  }
  __syncthreads();
  {
    const int dd = t >> 3;
    const float* q = Qt + (((size_t)b * NH + h) * DH + dd) * CD;
    const float bq = bqkv[h * DH + dd];
#pragma unroll
    for (int u = 0; u < 4; ++u) {
      const int e = (t & 7) * 4 + u;
      const float bk = bqkv[CD + h * DH + e];
      const float* kw = Wqkv + (size_t)(CD + h * DH + e) * CD;
      float sv = 0.f;
      for (int cc = 0; cc < CD; ++cc) sv += q[cc] * kw[cc];
      sv += bq * wkr[e] + bk * wqr[dd] + (float)ND * bq * bk;
      S[dd][e] = sv * SCALE;
    }
  }
  __syncthreads();
  if (t < 32) {
    float mx = -1e30f;
#pragma unroll
    for (int e = 0; e < 32; ++e) mx = fmaxf(mx, S[t][e]);
    float sum = 0.f;
#pragma unroll
    for (int e = 0; e < 32; ++e) sum += __expf(S[t][e] - mx);
    const float inv = 1.f / sum;
#pragma unroll
    for (int e = 0; e < 32; ++e) A[t][e] = __expf(S[t][e] - mx) * inv;
  }
  __syncthreads();
  {
    float wrow[32];
#pragma unroll
    for (int dd = 0; dd < 32; ++dd) wrow[dd] = Wout[(size_t)t * CD + dd * NH + h];
    for (int e = 0; e < 32; ++e) {
      float sv = 0.f;
#pragma unroll
      for (int dd = 0; dd < 32; ++dd) sv += wrow[dd] * A[dd][e];
      M[((size_t)b * CD + t) * CD + h * DH + e] = sv;
    }
  }
}

// P = M @ Wv stored fp16 in MFMA-fragment order Pf[b][kq][o][8] (kq = c>>3),
// cvec = M @ bv + bout.
__global__ __launch_bounds__(256) void pproj_k(const float* __restrict__ Wqkv,
                                               const float* __restrict__ bqkv,
                                               const float* __restrict__ bout,
                                               const float* __restrict__ M,
                                               unsigned short* __restrict__ Pf,
                                               float* __restrict__ cvec) {
  const int oq = blockIdx.x, b = blockIdx.y;
  const int t = threadIdx.x;                 // t = c
  const float* Mb = M + (size_t)b * CD * CD + oq * 16 * CD;
  const float* Wv = Wqkv + (size_t)2 * CD * CD;
  float acc[16];
#pragma unroll
  for (int i = 0; i < 16; ++i) acc[i] = 0.f;
  for (int m = 0; m < CD; ++m) {
    const float wvv = Wv[(size_t)m * CD + t];
#pragma unroll
    for (int o = 0; o < 16; ++o) acc[o] += Mb[o * CD + m] * wvv;
  }
#pragma unroll
  for (int o = 0; o < 16; ++o) {
    const int oo = oq * 16 + o;
    Pf[(((size_t)b * 32 + (t >> 3)) * 256 + oo) * 8 + (t & 7)] = f2h(acc[o]);
  }
  if (t < 16) {
    const int oo = oq * 16 + t;
    const float* mr = M + (size_t)b * CD * CD + oo * CD;
    float sv = bout[oo];
    for (int m = 0; m < CD; ++m) sv += mr[m] * bqkv[2 * CD + m];
    cvec[b * CD + oo] = sv;
  }
}

// out[b][o][n] = sum_c P[o][c] * fp16(x[b][c][n]) + cvec[b][o]
// Tile: 256 o x 128 n, K=256 fully LDS-resident -> barrier-free K-loop.
__global__ __launch_bounds__(512) void out_k(const float* __restrict__ x,
                                             const unsigned short* __restrict__ Pf,
                                             const float* __restrict__ cvec,
                                             float* __restrict__ out) {
  __shared__ unsigned short xT[128 * 256];   // 64 KB
  const int t = threadIdx.x;
  const int nb = blockIdx.x, b = blockIdx.y;
  const int n0 = nb * 128;
  const int w = t >> 6, l = t & 63, l15 = l & 15, l4 = l >> 4;

  {
    const int nbase = (w & 1) * 64 + l15 * 4;
    const int cb0   = (w >> 1) * 16 + l4 * 4;
#pragma unroll
    for (int it = 0; it < 4; ++it) {
      const int cb = cb0 + it * 64;
      const float* p = x + ((size_t)b * CD + cb) * ND + n0 + nbase;
      fx4 r0 = *(const fx4*)(p);
      fx4 r1 = *(const fx4*)(p + ND);
      fx4 r2 = *(const fx4*)(p + 2 * (size_t)ND);
      fx4 r3 = *(const fx4*)(p + 3 * (size_t)ND);
#pragma unroll
      for (int j = 0; j < 4; ++j) {
        const unsigned long long wlo =
            (unsigned long long)f2h(r0[j]) |
            ((unsigned long long)f2h(r1[j]) << 16) |
            ((unsigned long long)f2h(r2[j]) << 32) |
            ((unsigned long long)f2h(r3[j]) << 48);
        const int n = nbase + j;
        const int slot = ((cb >> 3) ^ (n & 15)) & 31;
        *(unsigned long long*)(&xT[n * 256 + slot * 8 + (cb & 7)]) = wlo;
      }
    }
  }
  __syncthreads();

  const int wr = w >> 1, wc = w & 1;
  fx4 acc[4][4];
#pragma unroll
  for (int i = 0; i < 4; ++i)
#pragma unroll
    for (int j = 0; j < 4; ++j) acc[i][j] = (fx4){0.f, 0.f, 0.f, 0.f};

  const unsigned short* Pb = Pf + (size_t)b * 32 * 256 * 8;
  h8 afc[4], afn[4];
#pragma unroll
  for (int i = 0; i < 4; ++i) {
    const int o = wr * 64 + i * 16 + l15;
    afc[i] = *(const h8*)(Pb + ((size_t)(l4) * 256 + o) * 8);
  }
#pragma unroll
  for (int st = 0; st < 8; ++st) {
    if (st < 7) {
      const int kq = (st + 1) * 4 + l4;
#pragma unroll
      for (int i = 0; i < 4; ++i) {
        const int o = wr * 64 + i * 16 + l15;
        afn[i] = *(const h8*)(Pb + ((size_t)kq * 256 + o) * 8);
      }
    }
#pragma unroll
    for (int j = 0; j < 4; ++j) {
      const int n = wc * 64 + j * 16 + l15;
      const int slot = ((st * 4 + l4) ^ (n & 15)) & 31;
      h8 bf_ = *(const h8*)(&xT[n * 256 + slot * 8]);
#pragma unroll
      for (int i = 0; i < 4; ++i)
        acc[i][j] = __builtin_amdgcn_mfma_f32_16x16x32_f16(afc[i], bf_, acc[i][j], 0, 0, 0);
    }
#pragma unroll
    for (int i = 0; i < 4; ++i) afc[i] = afn[i];
  }

  const float* cp = cvec + b * CD;
  float* ob = out + (size_t)b * CD * ND + n0;
#pragma unroll
  for (int i = 0; i < 4; ++i)
#pragma unroll
    for (int q = 0; q < 4; ++q) {
      const int o = wr * 64 + i * 16 + l4 * 4 + q;
      const float ad = cp[o];
#pragma unroll
      for (int j = 0; j < 4; ++j) {
        const int n = wc * 64 + j * 16 + l15;
        __builtin_nontemporal_store(acc[i][j][q] + ad, &ob[(size_t)o * ND + n]);
      }
    }
}

extern "C" void kernel_launch(void* const* d_in, const int* in_sizes, int n_in,
                              void* d_out, int out_size, void* d_ws, size_t ws_size,
                              hipStream_t stream) {
  const float* x    = (const float*)d_in[0];
  const float* Wqkv = (const float*)d_in[1];
  const float* bqkv = (const float*)d_in[2];
  const float* Wout = (const float*)d_in[3];
  const float* bout = (const float*)d_in[4];
  float* out = (float*)d_out;

  char* ws = (char*)d_ws;
  float*          Gsum = (float*)(ws + 0);                // 2 MB
  float*          r    = (float*)(ws + 2097152);          // 8 KB
  float*          rpart= (float*)(ws + 2105344);          // 256 KB
  float*          Qt   = (float*)(ws + 2367488);          // 2 MB
  float*          Mm   = (float*)(ws + 4464640);          // 2 MB
  unsigned short* Pf   = (unsigned short*)(ws + 6561792); // 1 MB
  float*          cvec = (float*)(ws + 7610368);          // 8 KB
  _Float16*       Gpart= (_Float16*)(ws + 7618560);       // 32 MB (fp16, GS=32)
  const size_t NEED = 7618560ULL + (size_t)BD * GS * CD * CD * 2;  // ~41.2 MB

  const bool partial = (ws_size >= NEED);
  if (partial) {
    gram_k<<<dim3(GS, BD), 512, 0, stream>>>(x, Gpart, Gsum, r, rpart, 0);
    reduce_k<<<dim3(512), 256, 0, stream>>>(Gpart, rpart, Gsum, r);
  } else {
    zero_k<<<dim3(2056), 256, 0, stream>>>(Gsum, 526336);  // Gsum + r
    gram_k<<<dim3(GS, BD), 512, 0, stream>>>(x, Gpart, Gsum, r, rpart, 1);
  }
  qg_k   <<<dim3(4, NH, BD),  256, 0, stream>>>(Wqkv, Gsum, Qt);
  attn_k <<<dim3(NH, BD),     256, 0, stream>>>(Wqkv, bqkv, Wout, Qt, r, Mm);
  pproj_k<<<dim3(16, BD),     256, 0, stream>>>(Wqkv, bqkv, bout, Mm, Pf, cvec);
  out_k  <<<dim3(ND / 128, BD), 512, 0, stream>>>(x, Pf, cvec, out);
}